// Round 6
// baseline (224.920 us; speedup 1.0000x reference)
//
#include <hip/hip_runtime.h>
#include <hip/hip_bf16.h>
#include <hip/hip_fp8.h>

// Self-attention: q=X@Wq.T+bq, k=..., v=...; S = causal_softmax(q k^T / 32); O = S v
// B=4, S=2048, D_IN=D_OUT=1024. fp32 in/out; internal bf16/fp8 MFMA + fp32 acc.
//
// R19 = R15 resubmitted verbatim. R15/R16/R17 failed on GPU acquisition
// (broker at capacity); R18 failed with "container failed twice" (ambiguous:
// overloaded host vs kernel hang — code audit found no hang path; vmcnt
// ledger, barrier uniformity, ring safety, LDS geometry all check out).
// Decision rule: another container failure => revert qkv to R14 core next round.
//
// R15 change: QKV projection ported to an 8-phase-style pipelined schedule
// (T3+T4+T5): 128x384 fused tile (Q|K|V cols), 8 waves (512 thr), BK=32,
// 4-deep LDS ring buffer (128 KB). Per K-tile: 2 phases of
// {ds_read frags || stage 2 x global_load_lds of tile t+3 -> s_barrier ->
//  lgkmcnt(0) -> setprio(1) -> 12 MFMA -> setprio(0) -> s_barrier}.
// Counted vmcnt(8) once per tile (never 0 in main loop); epilogue drains
// 8->4->0. Grid 512 = 2 clean rounds at 1 block/CU; XCD-chunked swizzle
// (mt-grouped) for A-panel L2 reuse. Ring-safety: tile t+3 stages into
// buffer (t-1)&3, free since tile t-1's closing barrier; tile t+1's loads
// are protected by vmcnt(8)+barrier (exactly 8 newer loads in flight).
// scores / pv / convert identical to R14.
//
// MFMA fragment layouts (HW-verified per guide §3):
//  A: lane holds A[m=lane&15][k=(lane>>4)*8+j], j=0..7
//  B: lane holds B[k=(lane>>4)*8+j][n=lane&15]
//  C/D: lane holds D[row=(lane>>4)*4+e][col=lane&15], e=0..3

typedef __attribute__((ext_vector_type(8))) short short8;   // 8 bf16 = 4 VGPRs
typedef __attribute__((ext_vector_type(4))) float floatx4;  // MFMA acc
typedef __attribute__((ext_vector_type(2))) long longx2;    // 16B = 2 fp8 frags

#define SEQ   2048
#define DMODEL 1024
#define NBATCH 4
#define MTOT  (SEQ * NBATCH)

#define BARRIER() asm volatile("s_barrier" ::: "memory")
#define LGKM0() do { asm volatile("s_waitcnt lgkmcnt(0)" ::: "memory"); \
                     __builtin_amdgcn_sched_barrier(0); } while (0)

// Direct global->LDS async copy, 16B per lane. LDS dst is wave-uniform base +
// lane*16 (per-lane scatter NOT supported).
__device__ __forceinline__ void stage16(const void* g, void* l)
{
  __builtin_amdgcn_global_load_lds(
      (const __attribute__((address_space(1))) void*)g,
      (__attribute__((address_space(3))) void*)l, 16, 0, 0);
}

__device__ __forceinline__ unsigned short bf16_bits(float f)
{
  __hip_bfloat16 h = __float2bfloat16(f);
  return *(unsigned short*)&h;
}

__device__ __forceinline__ unsigned char fp8_bits(float f)
{
  __hip_fp8_e4m3 h(f);            // OCP e4m3 (gfx950), not fnuz
  return h.__x;
}

// ---------------------------------------------------------------------------
// One-kernel fp32 -> bf16 convert for all four inputs. Each block: 1024 elems.
__global__ __launch_bounds__(256) void convert_all(
    const float* __restrict__ X,  const float* __restrict__ Wq,
    const float* __restrict__ Wk, const float* __restrict__ Wv,
    __hip_bfloat16* __restrict__ Xb,  __hip_bfloat16* __restrict__ Wqb,
    __hip_bfloat16* __restrict__ Wkb, __hip_bfloat16* __restrict__ Wvb)
{
  const int b = blockIdx.x;
  const float* src; __hip_bfloat16* dst; int rel;
  if (b < 8192)       { src = X;  dst = Xb;  rel = b; }
  else if (b < 9216)  { src = Wq; dst = Wqb; rel = b - 8192; }
  else if (b < 10240) { src = Wk; dst = Wkb; rel = b - 9216; }
  else                { src = Wv; dst = Wvb; rel = b - 10240; }
  const int i = rel * 1024 + threadIdx.x * 4;
  float4 f = *(const float4*)(src + i);
  uint2 o;
  o.x = (unsigned)bf16_bits(f.x) | ((unsigned)bf16_bits(f.y) << 16);
  o.y = (unsigned)bf16_bits(f.z) | ((unsigned)bf16_bits(f.w) << 16);
  *(uint2*)(dst + i) = o;
}

// ---------------------------------------------------------------------------
// Pipelined fused QKV: one K-tile step (BK=32). Two phases; each phase
// {ds_read frags, stage part of tile t+3, barrier, lgkm0, setprio, MFMA,
//  setprio, [vmcnt], barrier}. ENDW: -1 = no end wait, else vmcnt(ENDW).
template <int ENDW, bool STG>
__device__ __forceinline__ void qkv_tile_step(
    int t,
    __hip_bfloat16 (*ASb)[128 * 32], __hip_bfloat16 (*BSb)[384 * 32],
    const __hip_bfloat16* __restrict__ aSrc,
    const __hip_bfloat16* __restrict__ bSrc0,
    const __hip_bfloat16* __restrict__ bSrc1,
    const __hip_bfloat16* __restrict__ bSrc2,
    int wave, int wr, int wc, int quad, int r,
    floatx4 (&acc)[4][6])
{
  const __hip_bfloat16* As_ = ASb[t & 3];
  const __hip_bfloat16* Bs_ = BSb[t & 3];
  short8 a_[4], b_[3];
  // -------- phase 1: frag reads (4 A + 3 B), stage A + B(s0) of tile t+3
#pragma unroll
  for (int i = 0; i < 4; ++i)
    a_[i] = *(const short8*)(As_ + (wr * 64 + i * 16 + r) * 32 + quad * 8);
#pragma unroll
  for (int j = 0; j < 3; ++j)
    b_[j] = *(const short8*)(Bs_ + (wc * 96 + j * 16 + r) * 32 + quad * 8);
  if (STG) {
    const int tn = t + 3, bn = tn & 3;
    stage16(aSrc + tn * 32, ASb[bn] + wave * 512);
    stage16(bSrc0 + tn * 32, BSb[bn] + wave * 512);
  }
  BARRIER();
  LGKM0();
  __builtin_amdgcn_s_setprio(1);
#pragma unroll
  for (int i = 0; i < 4; ++i)
#pragma unroll
    for (int j = 0; j < 3; ++j)
      acc[i][j] = __builtin_amdgcn_mfma_f32_16x16x32_bf16(a_[i], b_[j], acc[i][j], 0, 0, 0);
  __builtin_amdgcn_s_setprio(0);
  BARRIER();
  // -------- phase 2: frag reads (3 B), stage B(s1,s2) of tile t+3
#pragma unroll
  for (int j = 0; j < 3; ++j)
    b_[j] = *(const short8*)(Bs_ + (wc * 96 + (j + 3) * 16 + r) * 32 + quad * 8);
  if (STG) {
    const int tn = t + 3, bn = tn & 3;
    stage16(bSrc1 + tn * 32, BSb[bn] + 4096 + wave * 512);
    stage16(bSrc2 + tn * 32, BSb[bn] + 8192 + wave * 512);
  }
  BARRIER();
  LGKM0();
  __builtin_amdgcn_s_setprio(1);
#pragma unroll
  for (int i = 0; i < 4; ++i)
#pragma unroll
    for (int j = 0; j < 3; ++j)
      acc[i][j + 3] = __builtin_amdgcn_mfma_f32_16x16x32_bf16(a_[i], b_[j], acc[i][j + 3], 0, 0, 0);
  __builtin_amdgcn_s_setprio(0);
  if (ENDW == 8)      asm volatile("s_waitcnt vmcnt(8)" ::: "memory");
  else if (ENDW == 4) asm volatile("s_waitcnt vmcnt(4)" ::: "memory");
  else if (ENDW == 0) asm volatile("s_waitcnt vmcnt(0)" ::: "memory");
  BARRIER();
}

// Fused QKV projection, pipelined. Tile 128x384 (128 cols of each of Q,K,V),
// 8 waves as (wr 0..1) x (wc 0..3), per-wave 64x96 out (acc[4][6]).
// LDS: 4-ring of A[128x32] + B[384x32] = 128 KB, 1 block/CU, grid 512
// (64 mt x 8 ngroup) = 2 clean CU rounds. Q,K stored fp8 e4m3 row-major,
// V stored bf16 transposed to Vt.
__global__ __launch_bounds__(512, 2) void gemm_qkv_8p(
    const __hip_bfloat16* __restrict__ Xb,
    const __hip_bfloat16* __restrict__ Wqb,
    const __hip_bfloat16* __restrict__ Wkb,
    const __hip_bfloat16* __restrict__ Wvb,
    const float* __restrict__ bq, const float* __restrict__ bk, const float* __restrict__ bv,
    unsigned char* __restrict__ Qb, unsigned char* __restrict__ Kb,
    __hip_bfloat16* __restrict__ Vt)
{
  __shared__ __hip_bfloat16 ASb[4][128 * 32];   // 32 KB
  __shared__ __hip_bfloat16 BSb[4][384 * 32];   // 96 KB (rows 0-127 Wq, 128-255 Wk, 256-383 Wv)

  // XCD-chunked bijective swizzle (512 % 8 == 0), mt-grouped: each XCD owns
  // 8 consecutive m-strips (A working set 2 MB, L2-resident, 8x reuse).
  const int b    = blockIdx.x;                 // 0..511
  const int orig = (b & 7) * 64 + (b >> 3);
  const int mt = orig >> 3, ng = orig & 7;
  const int m0 = mt * 128, n0 = ng * 128;

  const int tid = threadIdx.x;
  const int lane = tid & 63, wave = tid >> 6;
  const int quad = lane >> 4, r = lane & 15;
  const int wr = wave >> 2, wc = wave & 3;

  // Staging sources: thread tid loads LDS-linear slot tid (A) / s*512+tid (B);
  // row = idx>>2 (64 B rows), col-bytes = (idx&3)*16.
  const __hip_bfloat16* aSrc  = Xb  + (size_t)(m0 + (tid >> 2)) * DMODEL + (tid & 3) * 8;
  const __hip_bfloat16* bSrc0 = Wqb + (size_t)(n0 + (tid >> 2)) * DMODEL + (tid & 3) * 8;
  const __hip_bfloat16* bSrc1 = Wkb + (size_t)(n0 + (tid >> 2)) * DMODEL + (tid & 3) * 8;
  const __hip_bfloat16* bSrc2 = Wvb + (size_t)(n0 + (tid >> 2)) * DMODEL + (tid & 3) * 8;

  floatx4 acc[4][6] = {};

  // Prologue: stage tiles 0..2 into ring slots 0..2 (tile-major issue order),
  // then wait for tile 0 (12 issued, vmcnt(8) -> oldest 4 landed).
#pragma unroll
  for (int t0 = 0; t0 < 3; ++t0) {
    stage16(aSrc  + t0 * 32, ASb[t0] + wave * 512);
    stage16(bSrc0 + t0 * 32, BSb[t0] + wave * 512);
    stage16(bSrc1 + t0 * 32, BSb[t0] + 4096 + wave * 512);
    stage16(bSrc2 + t0 * 32, BSb[t0] + 8192 + wave * 512);
  }
  asm volatile("s_waitcnt vmcnt(8)" ::: "memory");
  BARRIER();

  // Main loop: compute tile t, stage tile t+3; vmcnt(8) protects tile t+1.
  for (int t = 0; t < 29; ++t)
    qkv_tile_step<8, true>(t, ASb, BSb, aSrc, bSrc0, bSrc1, bSrc2,
                           wave, wr, wc, quad, r, acc);
  // Drain: 8 -> 4 -> 0 -> none.
  qkv_tile_step<4, false>(29, ASb, BSb, aSrc, bSrc0, bSrc1, bSrc2,
                          wave, wr, wc, quad, r, acc);
  qkv_tile_step<0, false>(30, ASb, BSb, aSrc, bSrc0, bSrc1, bSrc2,
                          wave, wr, wc, quad, r, acc);
  qkv_tile_step<-1, false>(31, ASb, BSb, aSrc, bSrc0, bSrc1, bSrc2,
                           wave, wr, wc, quad, r, acc);

  // Epilogue. colglob = wc*96 + j*16 + r spans the 3x128 col space; 16-col
  // fragments never straddle a 128 boundary -> W select is lane-uniform.
#pragma unroll
  for (int j = 0; j < 6; ++j) {
    const int colglob = wc * 96 + j * 16 + r;
    const int wsel = (wc * 96 + j * 16) >> 7;      // 0=Q 1=K 2=V, lane-uniform
    const int n = n0 + (colglob & 127);
    if (wsel < 2) {
      unsigned char* out = wsel ? Kb : Qb;
      const float bb = (wsel ? bk : bq)[n];
#pragma unroll
      for (int i = 0; i < 4; ++i) {
        const int mb = m0 + wr * 64 + i * 16 + quad * 4;
#pragma unroll
        for (int e = 0; e < 4; ++e)
          out[(size_t)(mb + e) * DMODEL + n] = fp8_bits(acc[i][j][e] + bb);
      }
    } else {
      const int z = m0 >> 11;                      // SEQ = 2048; tile never crosses batch
      const int posb0 = (m0 & (SEQ - 1)) + wr * 64;
      __hip_bfloat16* vt = Vt + (size_t)z * DMODEL * SEQ;
      const float bb = bv[n];
#pragma unroll
      for (int i = 0; i < 4; ++i) {
        const int pos = posb0 + i * 16 + quad * 4;
        unsigned long long pk =
            (unsigned long long)bf16_bits(acc[i][j][0] + bb)
          | ((unsigned long long)bf16_bits(acc[i][j][1] + bb) << 16)
          | ((unsigned long long)bf16_bits(acc[i][j][2] + bb) << 32)
          | ((unsigned long long)bf16_bits(acc[i][j][3] + bb) << 48);
        *(unsigned long long*)(vt + (size_t)n * SEQ + pos) = pk;
      }
    }
  }
}

// ---------------------------------------------------------------------------
// 4-wave fp8 GEMM core: C[128x128] += A * B^T, A/B e4m3 row-major [.,K],
// BK=64. Same per-wave byte geometry as the qkv core (64 B rows, linear
// global_load_lds dst, b128 ds_reads at row*64+quad*16), 16 KB LDS.
// Each 16B register pair = 2 fp8 A/B-frags (kk=0,1) -> 32 MFMA/wave/barrier.
// k within a 16B group is permuted vs native MFMA order — consistent for A
// and B, so the accumulated dot product is exact.
__device__ __forceinline__ void gemm_core_4w_fp8(
    const unsigned char* __restrict__ A,
    const unsigned char* __restrict__ B,
    int K, int m0, int n0, int kchunks,
    unsigned char* As /*128x64B*/, unsigned char* Bs /*128x64B*/,
    floatx4 acc[4][4])
{
  const int tid  = threadIdx.x;
  const int lane = tid & 63;
  const int wave = tid >> 6;          // 0..3
  const int quad = lane >> 4;
  const int r    = lane & 15;
  const int wm   = (wave >> 1) * 64;
  const int wn   = (wave & 1) * 64;
  const int lrow = lane >> 2;         // 0..15
  const int lcol = (lane & 3) * 16;   // byte col 0,16,32,48

  const unsigned char* aB = A + (size_t)(m0 + wave * 32 + lrow) * K + lcol;
  const unsigned char* bB = B + (size_t)(n0 + wave * 32 + lrow) * K + lcol;
  unsigned char* lA = As + wave * 2048;   // 2 chunks of 1024 B
  unsigned char* lB = Bs + wave * 2048;

  for (int kt = 0; kt < kchunks; ++kt) {
    const int k0 = kt * 64;
#pragma unroll
    for (int s = 0; s < 2; ++s) {
      stage16(aB + (size_t)(16 * s) * K + k0, lA + s * 1024);
      stage16(bB + (size_t)(16 * s) * K + k0, lB + s * 1024);
    }
    __syncthreads();
    longx2 a[4], b[4];
#pragma unroll
    for (int i = 0; i < 4; ++i) {
      a[i] = __builtin_bit_cast(longx2, *(const int4*)(As + (wm + i * 16 + r) * 64 + quad * 16));
      b[i] = __builtin_bit_cast(longx2, *(const int4*)(Bs + (wn + i * 16 + r) * 64 + quad * 16));
    }
#pragma unroll
    for (int kk = 0; kk < 2; ++kk)
#pragma unroll
      for (int i = 0; i < 4; ++i)
#pragma unroll
        for (int j = 0; j < 4; ++j)
          acc[i][j] = __builtin_amdgcn_mfma_f32_16x16x32_fp8_fp8(
              a[i][kk], b[j][kk], acc[i][j], 0, 0, 0);
    __syncthreads();
  }
}

// ---------------------------------------------------------------------------
// 4-wave bf16 GEMM core: C[128x128] += A * B^T, BK=32, 16 KB LDS.
// If SUMS: also acc_s[i] += A-frag x ones (row sums of A in C-layout, fp32;
// each wave sums its own wm rows — waves sharing wm compute it redundantly).
template <bool SUMS>
__device__ __forceinline__ void gemm_core_4w(
    const __hip_bfloat16* __restrict__ A,
    const __hip_bfloat16* __restrict__ B,
    int K, int m0, int n0, int kchunks,
    __hip_bfloat16* As /*128x32*/, __hip_bfloat16* Bs /*128x32*/,
    floatx4 acc[4][4], floatx4 acc_s[4])
{
  const int tid  = threadIdx.x;
  const int lane = tid & 63;
  const int wave = tid >> 6;          // 0..3
  const int quad = lane >> 4;
  const int r    = lane & 15;
  const int wm   = (wave >> 1) * 64;
  const int wn   = (wave & 1) * 64;
  const int lrow = lane >> 2;         // 0..15
  const int lcol = (lane & 3) * 8;    // 0,8,16,24

  short8 ones;
#pragma unroll
  for (int t = 0; t < 8; ++t) ones[t] = (short)0x3F80;  // bf16 1.0

  const __hip_bfloat16* aB = A + (size_t)(m0 + wave * 32 + lrow) * K + lcol;
  const __hip_bfloat16* bB = B + (size_t)(n0 + wave * 32 + lrow) * K + lcol;
  __hip_bfloat16* lA = As + wave * 1024;   // 2 chunks of 512 elems
  __hip_bfloat16* lB = Bs + wave * 1024;

  for (int kt = 0; kt < kchunks; ++kt) {
    const int k0 = kt * 32;
#pragma unroll
    for (int s = 0; s < 2; ++s) {
      stage16(aB + (size_t)(16 * s) * K + k0, lA + s * 512);
      stage16(bB + (size_t)(16 * s) * K + k0, lB + s * 512);
    }
    __syncthreads();
    short8 a[4], b[4];
#pragma unroll
    for (int i = 0; i < 4; ++i) {
      a[i] = *(const short8*)(As + (wm + i * 16 + r) * 32 + quad * 8);
      b[i] = *(const short8*)(Bs + (wn + i * 16 + r) * 32 + quad * 8);
    }
    if (SUMS) {
#pragma unroll
      for (int i = 0; i < 4; ++i)
        acc_s[i] = __builtin_amdgcn_mfma_f32_16x16x32_bf16(a[i], ones, acc_s[i], 0, 0, 0);
    }
#pragma unroll
    for (int i = 0; i < 4; ++i)
#pragma unroll
      for (int j = 0; j < 4; ++j)
        acc[i][j] = __builtin_amdgcn_mfma_f32_16x16x32_bf16(a[i], b[j], acc[i][j], 0, 0, 0);
    __syncthreads();
  }
}

// ---------------------------------------------------------------------------
// Scores: P'[z][q][k] = exp((Q_z K_z^T)[q][k]/32) for k<=q (0 in the masked
// part of diagonal tiles), stored bf16. Q,K fp8 e4m3; BK=64 4-wave core.
// 128x128 tiles; 136 lower-tri tiles per batch, compact linear index.
// XCD-contiguous ordering: blocks sharing a Q row-panel run on one XCD.
// grid = (544), 256 threads, 16 KB LDS.
__global__ __launch_bounds__(256, 2) void gemm_scores(
    const unsigned char* __restrict__ Qb, const unsigned char* __restrict__ Kb,
    __hip_bfloat16* __restrict__ Sb)
{
  // bijective XCD swizzle: XCD(b)=b&7 gets the contiguous orig range
  // [x*68, x*68+68) -> consecutive same-mt tiles stay in one L2.
  const int b    = blockIdx.x;                 // 0..543
  const int orig = (b & 7) * 68 + (b >> 3);    // 544 = 8*68
  const int z    = orig / 136;
  const int L    = orig - z * 136;
  // tri decode: largest mt with mt(mt+1)/2 <= L
  int mt = (int)((sqrtf(8.0f * (float)L + 1.0f) - 1.0f) * 0.5f);
  while ((mt + 1) * (mt + 2) / 2 <= L) ++mt;
  while (mt * (mt + 1) / 2 > L) --mt;
  const int nt = L - mt * (mt + 1) / 2;
  const int m0 = mt * 128, n0 = nt * 128;

  __shared__ __align__(16) unsigned char As[128 * 64];
  __shared__ __align__(16) unsigned char Bs[128 * 64];
  const unsigned char* A = Qb + (size_t)z * SEQ * DMODEL;
  const unsigned char* B = Kb + (size_t)z * SEQ * DMODEL;
  __hip_bfloat16* outp = Sb + (size_t)z * SEQ * SEQ;
  floatx4 acc[4][4] = {};
  gemm_core_4w_fp8(A, B, DMODEL, m0, n0, DMODEL / 64, As, Bs, acc);

  const int lane = threadIdx.x & 63, wave = threadIdx.x >> 6;
  const int quad = lane >> 4, r = lane & 15;
  const int wm = (wave >> 1) * 64, wn = (wave & 1) * 64;
  const float scale = 0.03125f;  // 1/sqrt(1024)
#pragma unroll
  for (int i = 0; i < 4; ++i) {
    const int mbase = m0 + wm + i * 16 + quad * 4;
#pragma unroll
    for (int e = 0; e < 4; ++e) {
      const int row = mbase + e;
#pragma unroll
      for (int j = 0; j < 4; ++j) {
        const int n = n0 + wn + j * 16 + r;
        const float pv = (n <= row) ? __expf(acc[i][j][e] * scale) : 0.f;
        outp[(size_t)row * SEQ + n] = __float2bfloat16(pv);
      }
    }
  }
}

// ---------------------------------------------------------------------------
// PV: Out[z][q][d] = (P'_z @ Vt_z^T)[q][d] / rowsum(P'), fp32 out.
// Row sums via the ones-MFMA (acc_s, C-layout). 128x128 tiles, 4-wave bf16
// BK=32 core; K truncated at the diagonal.
// Work decomposition: 64 (z,mt) groups of 8 n-blocks each. Groups are dealt
// to XCDs round-robin by DESCENDING K (q%8 = XCD): per-XCD work balanced to
// within 12%, longest groups start first, and the 8 blocks sharing one Sb
// row-panel are consecutive on one XCD (A served from L2 after first fetch).
// grid = (512), 256 threads, 16 KB LDS.
__global__ __launch_bounds__(256, 2) void gemm_pv(
    const __hip_bfloat16* __restrict__ Sb, const __hip_bfloat16* __restrict__ Vt,
    float* __restrict__ Out)
{
  const int b    = blockIdx.x;     // 0..511
  const int xcd  = b & 7;
  const int slot = b >> 3;         // 0..63 within XCD
  const int gi   = slot >> 3;      // group index within XCD, 0..7
  const int q    = gi * 8 + xcd;   // global group rank, 0..63 (descending K)
  const int n0   = (slot & 7) * 128;
  const int z    = q & 3;
  const int mt   = 15 - (q >> 2);  // rank 0 -> mt=15 (longest K)
  const int m0   = mt * 128;

  __shared__ __align__(16) __hip_bfloat16 As[128 * 32];
  __shared__ __align__(16) __hip_bfloat16 Bs[128 * 32];
  const __hip_bfloat16* A = Sb + (size_t)z * SEQ * SEQ;
  const __hip_bfloat16* B = Vt + (size_t)z * DMODEL * SEQ;
  float* outp = Out + (size_t)z * SEQ * DMODEL;

  floatx4 acc[4][4] = {};
  floatx4 acc_s[4] = {};
  const int kchunks = 4 * mt + 4;   // (m0+128)/32: causal truncation
  gemm_core_4w<true>(A, B, SEQ, m0, n0, kchunks, As, Bs, acc, acc_s);

  const int lane = threadIdx.x & 63, wave = threadIdx.x >> 6;
  const int quad = lane >> 4, r = lane & 15;
  const int wm = (wave >> 1) * 64, wn = (wave & 1) * 64;
#pragma unroll
  for (int i = 0; i < 4; ++i) {
    const int mbase = m0 + wm + i * 16 + quad * 4;
    float inv[4];
#pragma unroll
    for (int e = 0; e < 4; ++e) inv[e] = 1.f / acc_s[i][e];
#pragma unroll
    for (int j = 0; j < 4; ++j) {
      const int n = n0 + wn + j * 16 + r;
#pragma unroll
      for (int e = 0; e < 4; ++e)
        outp[(size_t)(mbase + e) * DMODEL + n] = acc[i][j][e] * inv[e];
    }
  }
}

// ---------------------------------------------------------------------------
extern "C" void kernel_launch(void* const* d_in, const int* in_sizes, int n_in,
                              void* d_out, int out_size, void* d_ws, size_t ws_size,
                              hipStream_t stream)
{
  const float* X  = (const float*)d_in[0];
  const float* Wq = (const float*)d_in[1];
  const float* bq = (const float*)d_in[2];
  const float* Wk = (const float*)d_in[3];
  const float* bk = (const float*)d_in[4];
  const float* Wv = (const float*)d_in[5];
  const float* bv = (const float*)d_in[6];
  float* Out = (float*)d_out;

  // Workspace layout (~87 MB total)
  char* ws = (char*)d_ws;
  size_t off = 0;
  auto alloc = [&](size_t bytes) -> void* {
    void* p = ws + off;
    off += (bytes + 255) & ~(size_t)255;
    return p;
  };
  __hip_bfloat16* Xb  = (__hip_bfloat16*)alloc((size_t)MTOT * DMODEL * 2);    // 16 MB
  __hip_bfloat16* Wqb = (__hip_bfloat16*)alloc((size_t)DMODEL * DMODEL * 2);  // 2 MB
  __hip_bfloat16* Wkb = (__hip_bfloat16*)alloc((size_t)DMODEL * DMODEL * 2);
  __hip_bfloat16* Wvb = (__hip_bfloat16*)alloc((size_t)DMODEL * DMODEL * 2);
  unsigned char*  Qb  = (unsigned char*)alloc((size_t)MTOT * DMODEL);         // 8 MB (fp8)
  unsigned char*  Kb  = (unsigned char*)alloc((size_t)MTOT * DMODEL);         // 8 MB (fp8)
  __hip_bfloat16* Vt  = (__hip_bfloat16*)alloc((size_t)MTOT * DMODEL * 2);    // 16 MB
  __hip_bfloat16* Sb  = (__hip_bfloat16*)alloc((size_t)NBATCH * SEQ * SEQ * 2); // 32 MB
  (void)ws_size; (void)in_sizes; (void)n_in; (void)out_size;

  // 1) converts (one kernel)
  convert_all<<<11264, 256, 0, stream>>>(X, Wq, Wk, Wv, Xb, Wqb, Wkb, Wvb);
  // 2) fused QKV projection, pipelined (T3+T4+T5); Q,K fp8 e4m3, V -> Vt
  gemm_qkv_8p<<<512, 512, 0, stream>>>(
      Xb, Wqb, Wkb, Wvb, bq, bk, bv, Qb, Kb, Vt);
  // 3) scores: fp8 BK=64 4-wave 128x128 core, tri-compact + XCD-contiguous
  gemm_scores<<<dim3(544), 256, 0, stream>>>(Qb, Kb, Sb);
  // 4) PV: bf16 4-wave 128x128 core, XCD-balanced longest-first,
  //    in-kernel row sums + normalize
  gemm_pv<<<dim3(512), 256, 0, stream>>>(Sb, Vt, Out);
}

// Round 7
// 216.088 us; speedup vs baseline: 1.0409x; 1.0409x over previous
//
#include <hip/hip_runtime.h>
#include <hip/hip_bf16.h>
#include <hip/hip_fp8.h>

// Self-attention: q=X@Wq.T+bq, k=..., v=...; S = causal_softmax(q k^T / 32); O = S v
// B=4, S=2048, D_IN=D_OUT=1024. fp32 in/out; internal bf16/fp8 MFMA + fp32 acc.
//
// R20 change (post-mortem of R19's measured null): the R15 fine-phase pipeline
// (12 MFMA/barrier, 4 barriers/tile, 1 blk/CU) landed at 28% MfmaUtil = baseline.
// Revert to the PROVEN per-step cores (48 MFMA per barrier for qkv, 32 for
// scores, 16+ for pv) and apply the catalog's T3 "minimum 2-phase" transform
// to all three: double-buffered LDS, STAGE(t+1) issued BEFORE compute(t),
// single {vmcnt(0) lgkmcnt(0); barrier} per K-step at the end. The drain now
// waits on loads issued a full compute-block earlier (mostly L2/L3-resident
// X/W/Sb/Vt) instead of loads issued immediately before the barrier.
//  - qkv:   R13 geometry (4 waves, 128x128x3 fused tile, 8 stage16/step,
//           48 MFMA/step), dbuf 64 KB, XCD-chunked swizzle kept (FETCH 69->57).
//  - scores: fp8 BK=64 4-wave core, dbuf 32 KB, tri-compact grid + XCD swizzle.
//  - pv:    bf16 BK=32 4-wave core + ones-MFMA row sums, dbuf 32 KB,
//           XCD-balanced longest-first.
// Barrier count per step: 2 -> 1. convert unchanged.
//
// MFMA fragment layouts (HW-verified per guide §3):
//  A: lane holds A[m=lane&15][k=(lane>>4)*8+j], j=0..7
//  B: lane holds B[k=(lane>>4)*8+j][n=lane&15]
//  C/D: lane holds D[row=(lane>>4)*4+e][col=lane&15], e=0..3

typedef __attribute__((ext_vector_type(8))) short short8;   // 8 bf16 = 4 VGPRs
typedef __attribute__((ext_vector_type(4))) float floatx4;  // MFMA acc
typedef __attribute__((ext_vector_type(2))) long longx2;    // 16B = 2 fp8 frags

#define SEQ   2048
#define DMODEL 1024
#define NBATCH 4
#define MTOT  (SEQ * NBATCH)

// End-of-step fence: all my stage16s (vmcnt) and my ds_reads (lgkm) done,
// then block-wide barrier. sched_barrier stops hipcc migrating ops across.
#define STEP_FENCE() do {                                              \
    asm volatile("s_waitcnt vmcnt(0) lgkmcnt(0)" ::: "memory");        \
    __builtin_amdgcn_sched_barrier(0);                                 \
    __builtin_amdgcn_s_barrier(); } while (0)

// Direct global->LDS async copy, 16B per lane. LDS dst is wave-uniform base +
// lane*16 (per-lane scatter NOT supported).
__device__ __forceinline__ void stage16(const void* g, void* l)
{
  __builtin_amdgcn_global_load_lds(
      (const __attribute__((address_space(1))) void*)g,
      (__attribute__((address_space(3))) void*)l, 16, 0, 0);
}

__device__ __forceinline__ unsigned short bf16_bits(float f)
{
  __hip_bfloat16 h = __float2bfloat16(f);
  return *(unsigned short*)&h;
}

__device__ __forceinline__ unsigned char fp8_bits(float f)
{
  __hip_fp8_e4m3 h(f);            // OCP e4m3 (gfx950), not fnuz
  return h.__x;
}

// ---------------------------------------------------------------------------
// One-kernel fp32 -> bf16 convert for all four inputs. Each block: 1024 elems.
__global__ __launch_bounds__(256) void convert_all(
    const float* __restrict__ X,  const float* __restrict__ Wq,
    const float* __restrict__ Wk, const float* __restrict__ Wv,
    __hip_bfloat16* __restrict__ Xb,  __hip_bfloat16* __restrict__ Wqb,
    __hip_bfloat16* __restrict__ Wkb, __hip_bfloat16* __restrict__ Wvb)
{
  const int b = blockIdx.x;
  const float* src; __hip_bfloat16* dst; int rel;
  if (b < 8192)       { src = X;  dst = Xb;  rel = b; }
  else if (b < 9216)  { src = Wq; dst = Wqb; rel = b - 8192; }
  else if (b < 10240) { src = Wk; dst = Wkb; rel = b - 9216; }
  else                { src = Wv; dst = Wvb; rel = b - 10240; }
  const int i = rel * 1024 + threadIdx.x * 4;
  float4 f = *(const float4*)(src + i);
  uint2 o;
  o.x = (unsigned)bf16_bits(f.x) | ((unsigned)bf16_bits(f.y) << 16);
  o.y = (unsigned)bf16_bits(f.z) | ((unsigned)bf16_bits(f.w) << 16);
  *(uint2*)(dst + i) = o;
}

// ---------------------------------------------------------------------------
// Fused QKV projection, prefetch-1 double-buffered (T3 minimum-2-phase).
// R13 geometry: 4 waves, tile 128(m) x 128(n) x {Q,K,V}, BK=32,
// 48 MFMA/wave/step between single barriers. LDS 2 x (8+24) = 64 KB.
// Q,K stored fp8 e4m3 row-major; V stored bf16 transposed to Vt.
// grid = 512 flat (XCD-chunked: mt-grouped per XCD), 256 threads.
__global__ __launch_bounds__(256, 2) void gemm_qkv_db(
    const __hip_bfloat16* __restrict__ Xb,
    const __hip_bfloat16* __restrict__ Wqb,
    const __hip_bfloat16* __restrict__ Wkb,
    const __hip_bfloat16* __restrict__ Wvb,
    const float* __restrict__ bq, const float* __restrict__ bk, const float* __restrict__ bv,
    unsigned char* __restrict__ Qb, unsigned char* __restrict__ Kb,
    __hip_bfloat16* __restrict__ Vt)
{
  __shared__ __hip_bfloat16 As[2][128 * 32];      // 2 x 8 KB
  __shared__ __hip_bfloat16 Bs[2][3][128 * 32];   // 2 x 24 KB

  // XCD-chunked bijective swizzle (512 % 8 == 0), mt-grouped.
  const int b    = blockIdx.x;                 // 0..511
  const int orig = (b & 7) * 64 + (b >> 3);
  const int mt = orig >> 3, ng = orig & 7;
  const int m0 = mt * 128, n0 = ng * 128;

  const int tid  = threadIdx.x;
  const int lane = tid & 63;
  const int wave = tid >> 6;                   // 0..3
  const int quad = lane >> 4;
  const int r    = lane & 15;
  const int wm   = (wave >> 1) * 64;
  const int wn   = (wave & 1) * 64;
  const int srow = wave * 16 + (lane >> 2);    // 0..63
  const int scol = (lane & 3) * 8;             // 0,8,16,24

  const __hip_bfloat16* aR0 = Xb + (size_t)(m0 + srow) * DMODEL + scol;
  const __hip_bfloat16* aR1 = aR0 + (size_t)64 * DMODEL;
  const __hip_bfloat16* bR0[3], * bR1[3];
  {
    const __hip_bfloat16* Wp[3] = {Wqb, Wkb, Wvb};
#pragma unroll
    for (int w = 0; w < 3; ++w) {
      bR0[w] = Wp[w] + (size_t)(n0 + srow) * DMODEL + scol;
      bR1[w] = bR0[w] + (size_t)64 * DMODEL;
    }
  }

  floatx4 acc[3][4][4] = {};

  // Prologue: stage K-tile 0 into buffer 0, wait, publish.
  {
    stage16(aR0, As[0] + wave * 512);
    stage16(aR1, As[0] + 2048 + wave * 512);
#pragma unroll
    for (int w = 0; w < 3; ++w) {
      stage16(bR0[w], Bs[0][w] + wave * 512);
      stage16(bR1[w], Bs[0][w] + 2048 + wave * 512);
    }
    asm volatile("s_waitcnt vmcnt(0)" ::: "memory");
    __builtin_amdgcn_sched_barrier(0);
    __builtin_amdgcn_s_barrier();
  }

  for (int kt = 0; kt < 32; ++kt) {
    const int cur = kt & 1;
    // Issue next tile's staging FIRST (hides under this tile's compute).
    if (kt < 31) {
      const int k0 = (kt + 1) * 32, nb = cur ^ 1;
      stage16(aR0 + k0, As[nb] + wave * 512);
      stage16(aR1 + k0, As[nb] + 2048 + wave * 512);
#pragma unroll
      for (int w = 0; w < 3; ++w) {
        stage16(bR0[w] + k0, Bs[nb][w] + wave * 512);
        stage16(bR1[w] + k0, Bs[nb][w] + 2048 + wave * 512);
      }
    }
    // Compute current tile: 16 ds_read_b128 + 48 MFMA.
    short8 a[4];
#pragma unroll
    for (int i = 0; i < 4; ++i)
      a[i] = *(const short8*)(As[cur] + (wm + i * 16 + r) * 32 + quad * 8);
#pragma unroll
    for (int w = 0; w < 3; ++w) {
      short8 bb[4];
#pragma unroll
      for (int j = 0; j < 4; ++j)
        bb[j] = *(const short8*)(Bs[cur][w] + (wn + j * 16 + r) * 32 + quad * 8);
#pragma unroll
      for (int i = 0; i < 4; ++i)
#pragma unroll
        for (int j = 0; j < 4; ++j)
          acc[w][i][j] = __builtin_amdgcn_mfma_f32_16x16x32_bf16(a[i], bb[j], acc[w][i][j], 0, 0, 0);
    }
    STEP_FENCE();   // next tile landed (issued ~450 cyc ago) + my reads done
  }

  // Q, K: fp8 e4m3 row-major stores
  {
    unsigned char* Op[2] = {Qb, Kb};
    const float* Bp[2] = {bq, bk};
#pragma unroll
    for (int w = 0; w < 2; ++w) {
      unsigned char* out = Op[w];
#pragma unroll
      for (int j = 0; j < 4; ++j) {
        const int n = n0 + wn + j * 16 + r;
        const float bb = Bp[w][n];
#pragma unroll
        for (int i = 0; i < 4; ++i) {
          const int mbase = m0 + wm + i * 16 + quad * 4;
#pragma unroll
          for (int e = 0; e < 4; ++e)
            out[(size_t)(mbase + e) * DMODEL + n] = fp8_bits(acc[w][i][j][e] + bb);
        }
      }
    }
  }
  // V: transposed bf16 store Vt[z][d=n][pos], 8B packed per (i,j).
  {
    const int z    = m0 >> 11;           // SEQ = 2048
    const int posb = (m0 & (SEQ - 1)) + wm;
    __hip_bfloat16* vt = Vt + (size_t)z * DMODEL * SEQ;
#pragma unroll
    for (int j = 0; j < 4; ++j) {
      const int n = n0 + wn + j * 16 + r;
      const float bb = bv[n];
#pragma unroll
      for (int i = 0; i < 4; ++i) {
        const int pos = posb + i * 16 + quad * 4;
        unsigned long long pk =
            (unsigned long long)bf16_bits(acc[2][i][j][0] + bb)
          | ((unsigned long long)bf16_bits(acc[2][i][j][1] + bb) << 16)
          | ((unsigned long long)bf16_bits(acc[2][i][j][2] + bb) << 32)
          | ((unsigned long long)bf16_bits(acc[2][i][j][3] + bb) << 48);
        *(unsigned long long*)(vt + (size_t)n * SEQ + pos) = pk;
      }
    }
  }
}

// ---------------------------------------------------------------------------
// 4-wave fp8 GEMM core, prefetch-1 dbuf: C[128x128] += A * B^T, e4m3 [.,K],
// BK=64. Per step: stage t+1 (4 stage16) -> 8 ds_read_b128 -> 32 MFMA ->
// STEP_FENCE. LDS 2 x (8+8) = 32 KB.
__device__ __forceinline__ void gemm_core_4w_fp8_db(
    const unsigned char* __restrict__ A,
    const unsigned char* __restrict__ B,
    int K, int m0, int n0, int kchunks,
    unsigned char (*As)[128 * 64], unsigned char (*Bs)[128 * 64],
    floatx4 acc[4][4])
{
  const int tid  = threadIdx.x;
  const int lane = tid & 63;
  const int wave = tid >> 6;          // 0..3
  const int quad = lane >> 4;
  const int r    = lane & 15;
  const int wm   = (wave >> 1) * 64;
  const int wn   = (wave & 1) * 64;
  const int lrow = lane >> 2;         // 0..15
  const int lcol = (lane & 3) * 16;   // byte col 0,16,32,48

  const unsigned char* aB = A + (size_t)(m0 + wave * 32 + lrow) * K + lcol;
  const unsigned char* bB = B + (size_t)(n0 + wave * 32 + lrow) * K + lcol;

  // Prologue: stage tile 0.
#pragma unroll
  for (int s = 0; s < 2; ++s) {
    stage16(aB + (size_t)(16 * s) * K, As[0] + wave * 2048 + s * 1024);
    stage16(bB + (size_t)(16 * s) * K, Bs[0] + wave * 2048 + s * 1024);
  }
  asm volatile("s_waitcnt vmcnt(0)" ::: "memory");
  __builtin_amdgcn_sched_barrier(0);
  __builtin_amdgcn_s_barrier();

  for (int kt = 0; kt < kchunks; ++kt) {
    const int cur = kt & 1;
    if (kt + 1 < kchunks) {
      const int k0 = (kt + 1) * 64, nb = cur ^ 1;
#pragma unroll
      for (int s = 0; s < 2; ++s) {
        stage16(aB + (size_t)(16 * s) * K + k0, As[nb] + wave * 2048 + s * 1024);
        stage16(bB + (size_t)(16 * s) * K + k0, Bs[nb] + wave * 2048 + s * 1024);
      }
    }
    longx2 a[4], bb[4];
#pragma unroll
    for (int i = 0; i < 4; ++i) {
      a[i]  = __builtin_bit_cast(longx2, *(const int4*)(As[cur] + (wm + i * 16 + r) * 64 + quad * 16));
      bb[i] = __builtin_bit_cast(longx2, *(const int4*)(Bs[cur] + (wn + i * 16 + r) * 64 + quad * 16));
    }
#pragma unroll
    for (int kk = 0; kk < 2; ++kk)
#pragma unroll
      for (int i = 0; i < 4; ++i)
#pragma unroll
        for (int j = 0; j < 4; ++j)
          acc[i][j] = __builtin_amdgcn_mfma_f32_16x16x32_fp8_fp8(
              a[i][kk], bb[j][kk], acc[i][j], 0, 0, 0);
    STEP_FENCE();
  }
}

// ---------------------------------------------------------------------------
// 4-wave bf16 GEMM core, prefetch-1 dbuf: C[128x128] += A * B^T, BK=32.
// If SUMS: acc_s[i] += A-frag x ones (row sums of A in C-layout, fp32).
// LDS 2 x (8+8) = 32 KB.
template <bool SUMS>
__device__ __forceinline__ void gemm_core_4w_db(
    const __hip_bfloat16* __restrict__ A,
    const __hip_bfloat16* __restrict__ B,
    int K, int m0, int n0, int kchunks,
    __hip_bfloat16 (*As)[128 * 32], __hip_bfloat16 (*Bs)[128 * 32],
    floatx4 acc[4][4], floatx4 acc_s[4])
{
  const int tid  = threadIdx.x;
  const int lane = tid & 63;
  const int wave = tid >> 6;          // 0..3
  const int quad = lane >> 4;
  const int r    = lane & 15;
  const int wm   = (wave >> 1) * 64;
  const int wn   = (wave & 1) * 64;
  const int lrow = lane >> 2;         // 0..15
  const int lcol = (lane & 3) * 8;    // 0,8,16,24

  short8 ones;
#pragma unroll
  for (int t = 0; t < 8; ++t) ones[t] = (short)0x3F80;  // bf16 1.0

  const __hip_bfloat16* aB = A + (size_t)(m0 + wave * 32 + lrow) * K + lcol;
  const __hip_bfloat16* bB = B + (size_t)(n0 + wave * 32 + lrow) * K + lcol;

  // Prologue: stage tile 0.
#pragma unroll
  for (int s = 0; s < 2; ++s) {
    stage16(aB + (size_t)(16 * s) * K, As[0] + wave * 1024 + s * 512);
    stage16(bB + (size_t)(16 * s) * K, Bs[0] + wave * 1024 + s * 512);
  }
  asm volatile("s_waitcnt vmcnt(0)" ::: "memory");
  __builtin_amdgcn_sched_barrier(0);
  __builtin_amdgcn_s_barrier();

  for (int kt = 0; kt < kchunks; ++kt) {
    const int cur = kt & 1;
    if (kt + 1 < kchunks) {
      const int k0 = (kt + 1) * 32, nb = cur ^ 1;
#pragma unroll
      for (int s = 0; s < 2; ++s) {
        stage16(aB + (size_t)(16 * s) * K + k0, As[nb] + wave * 1024 + s * 512);
        stage16(bB + (size_t)(16 * s) * K + k0, Bs[nb] + wave * 1024 + s * 512);
      }
    }
    short8 a[4], bb[4];
#pragma unroll
    for (int i = 0; i < 4; ++i) {
      a[i]  = *(const short8*)(As[cur] + (wm + i * 16 + r) * 32 + quad * 8);
      bb[i] = *(const short8*)(Bs[cur] + (wn + i * 16 + r) * 32 + quad * 8);
    }
    if (SUMS) {
#pragma unroll
      for (int i = 0; i < 4; ++i)
        acc_s[i] = __builtin_amdgcn_mfma_f32_16x16x32_bf16(a[i], ones, acc_s[i], 0, 0, 0);
    }
#pragma unroll
    for (int i = 0; i < 4; ++i)
#pragma unroll
      for (int j = 0; j < 4; ++j)
        acc[i][j] = __builtin_amdgcn_mfma_f32_16x16x32_bf16(a[i], bb[j], acc[i][j], 0, 0, 0);
    STEP_FENCE();
  }
}

// ---------------------------------------------------------------------------
// Scores: P'[z][q][k] = exp((Q_z K_z^T)[q][k]/32) for k<=q (0 in the masked
// part of diagonal tiles), stored bf16. Q,K fp8 e4m3; BK=64 dbuf core.
// 128x128 tiles; 136 lower-tri tiles per batch; XCD-contiguous ordering.
// grid = (544), 256 threads, 32 KB LDS.
__global__ __launch_bounds__(256, 2) void gemm_scores(
    const unsigned char* __restrict__ Qb, const unsigned char* __restrict__ Kb,
    __hip_bfloat16* __restrict__ Sb)
{
  const int b    = blockIdx.x;                 // 0..543
  const int orig = (b & 7) * 68 + (b >> 3);    // 544 = 8*68, bijective
  const int z    = orig / 136;
  const int L    = orig - z * 136;
  int mt = (int)((sqrtf(8.0f * (float)L + 1.0f) - 1.0f) * 0.5f);
  while ((mt + 1) * (mt + 2) / 2 <= L) ++mt;
  while (mt * (mt + 1) / 2 > L) --mt;
  const int nt = L - mt * (mt + 1) / 2;
  const int m0 = mt * 128, n0 = nt * 128;

  __shared__ __align__(16) unsigned char As[2][128 * 64];
  __shared__ __align__(16) unsigned char Bs[2][128 * 64];
  const unsigned char* A = Qb + (size_t)z * SEQ * DMODEL;
  const unsigned char* B = Kb + (size_t)z * SEQ * DMODEL;
  __hip_bfloat16* outp = Sb + (size_t)z * SEQ * SEQ;
  floatx4 acc[4][4] = {};
  gemm_core_4w_fp8_db(A, B, DMODEL, m0, n0, DMODEL / 64, As, Bs, acc);

  const int lane = threadIdx.x & 63, wave = threadIdx.x >> 6;
  const int quad = lane >> 4, r = lane & 15;
  const int wm = (wave >> 1) * 64, wn = (wave & 1) * 64;
  const float scale = 0.03125f;  // 1/sqrt(1024)
#pragma unroll
  for (int i = 0; i < 4; ++i) {
    const int mbase = m0 + wm + i * 16 + quad * 4;
#pragma unroll
    for (int e = 0; e < 4; ++e) {
      const int row = mbase + e;
#pragma unroll
      for (int j = 0; j < 4; ++j) {
        const int n = n0 + wn + j * 16 + r;
        const float pv = (n <= row) ? __expf(acc[i][j][e] * scale) : 0.f;
        outp[(size_t)row * SEQ + n] = __float2bfloat16(pv);
      }
    }
  }
}

// ---------------------------------------------------------------------------
// PV: Out[z][q][d] = (P'_z @ Vt_z^T)[q][d] / rowsum(P'), fp32 out.
// Row sums via the ones-MFMA. 128x128 tiles, bf16 BK=32 dbuf core; K
// truncated at the diagonal. XCD-balanced longest-first (groups of 8
// n-blocks sharing one Sb row-panel stay on one XCD).
// grid = (512), 256 threads, 32 KB LDS.
__global__ __launch_bounds__(256, 2) void gemm_pv(
    const __hip_bfloat16* __restrict__ Sb, const __hip_bfloat16* __restrict__ Vt,
    float* __restrict__ Out)
{
  const int b    = blockIdx.x;     // 0..511
  const int xcd  = b & 7;
  const int slot = b >> 3;         // 0..63 within XCD
  const int gi   = slot >> 3;      // group index within XCD, 0..7
  const int q    = gi * 8 + xcd;   // global group rank, 0..63 (descending K)
  const int n0   = (slot & 7) * 128;
  const int z    = q & 3;
  const int mt   = 15 - (q >> 2);  // rank 0 -> mt=15 (longest K)
  const int m0   = mt * 128;

  __shared__ __align__(16) __hip_bfloat16 As[2][128 * 32];
  __shared__ __align__(16) __hip_bfloat16 Bs[2][128 * 32];
  const __hip_bfloat16* A = Sb + (size_t)z * SEQ * SEQ;
  const __hip_bfloat16* B = Vt + (size_t)z * DMODEL * SEQ;
  float* outp = Out + (size_t)z * SEQ * DMODEL;

  floatx4 acc[4][4] = {};
  floatx4 acc_s[4] = {};
  const int kchunks = 4 * mt + 4;   // (m0+128)/32: causal truncation
  gemm_core_4w_db<true>(A, B, SEQ, m0, n0, kchunks, As, Bs, acc, acc_s);

  const int lane = threadIdx.x & 63, wave = threadIdx.x >> 6;
  const int quad = lane >> 4, r = lane & 15;
  const int wm = (wave >> 1) * 64, wn = (wave & 1) * 64;
#pragma unroll
  for (int i = 0; i < 4; ++i) {
    const int mbase = m0 + wm + i * 16 + quad * 4;
    float inv[4];
#pragma unroll
    for (int e = 0; e < 4; ++e) inv[e] = 1.f / acc_s[i][e];
#pragma unroll
    for (int j = 0; j < 4; ++j) {
      const int n = n0 + wn + j * 16 + r;
#pragma unroll
      for (int e = 0; e < 4; ++e)
        outp[(size_t)(mbase + e) * DMODEL + n] = acc[i][j][e] * inv[e];
    }
  }
}

// ---------------------------------------------------------------------------
extern "C" void kernel_launch(void* const* d_in, const int* in_sizes, int n_in,
                              void* d_out, int out_size, void* d_ws, size_t ws_size,
                              hipStream_t stream)
{
  const float* X  = (const float*)d_in[0];
  const float* Wq = (const float*)d_in[1];
  const float* bq = (const float*)d_in[2];
  const float* Wk = (const float*)d_in[3];
  const float* bk = (const float*)d_in[4];
  const float* Wv = (const float*)d_in[5];
  const float* bv = (const float*)d_in[6];
  float* Out = (float*)d_out;

  // Workspace layout (~87 MB total)
  char* ws = (char*)d_ws;
  size_t off = 0;
  auto alloc = [&](size_t bytes) -> void* {
    void* p = ws + off;
    off += (bytes + 255) & ~(size_t)255;
    return p;
  };
  __hip_bfloat16* Xb  = (__hip_bfloat16*)alloc((size_t)MTOT * DMODEL * 2);    // 16 MB
  __hip_bfloat16* Wqb = (__hip_bfloat16*)alloc((size_t)DMODEL * DMODEL * 2);  // 2 MB
  __hip_bfloat16* Wkb = (__hip_bfloat16*)alloc((size_t)DMODEL * DMODEL * 2);
  __hip_bfloat16* Wvb = (__hip_bfloat16*)alloc((size_t)DMODEL * DMODEL * 2);
  unsigned char*  Qb  = (unsigned char*)alloc((size_t)MTOT * DMODEL);         // 8 MB (fp8)
  unsigned char*  Kb  = (unsigned char*)alloc((size_t)MTOT * DMODEL);         // 8 MB (fp8)
  __hip_bfloat16* Vt  = (__hip_bfloat16*)alloc((size_t)MTOT * DMODEL * 2);    // 16 MB
  __hip_bfloat16* Sb  = (__hip_bfloat16*)alloc((size_t)NBATCH * SEQ * SEQ * 2); // 32 MB
  (void)ws_size; (void)in_sizes; (void)n_in; (void)out_size;

  // 1) converts (one kernel)
  convert_all<<<11264, 256, 0, stream>>>(X, Wq, Wk, Wv, Xb, Wqb, Wkb, Wvb);
  // 2) fused QKV projection, prefetch-1 dbuf; Q,K fp8 e4m3, V -> Vt
  gemm_qkv_db<<<512, 256, 0, stream>>>(
      Xb, Wqb, Wkb, Wvb, bq, bk, bv, Qb, Kb, Vt);
  // 3) scores: fp8 BK=64 dbuf core, tri-compact + XCD-contiguous
  gemm_scores<<<dim3(544), 256, 0, stream>>>(Qb, Kb, Sb);
  // 4) PV: bf16 dbuf core, XCD-balanced longest-first, row sums + normalize
  gemm_pv<<<dim3(512), 256, 0, stream>>>(Sb, Vt, Out);
}